// Round 11
// baseline (393.622 us; speedup 1.0000x reference)
//
#include <hip/hip_runtime.h>
#include <hip/hip_bf16.h>
#include <hip/hip_cooperative_groups.h>

namespace cg = cooperative_groups;

#define N_NODES 8192
#define DIM 256
#define NLAB 2048
#define NGRAPH 16
#define NSLICE 16
#define NT 256
#define NB_MAX 512
#define INV_T 10.0f
#define ZN_INTS (NLAB * NGRAPH + NLAB + 4 + 2 * N_NODES)

typedef __attribute__((ext_vector_type(8))) short short8;
typedef __attribute__((ext_vector_type(4))) float f32x4;

__device__ __forceinline__ ushort f2bf(float f) {
    uint u = __float_as_uint(f);
    return (ushort)((u + 0x7FFFu + ((u >> 16) & 1u)) >> 16);  // RNE
}

// ---------------- workspace layout helper (device+host agree) ----------------
// [Epb: 8192*256 bf16 = 4MB][zeroed ints: cnt|tot|P_count|n_pos|acc_nce|acc_pos|s_glob|pos_glob]
// [idx_c][rc_c][meta]

// ===================== fused cooperative kernel =====================
__global__ __launch_bounds__(NT, 2) void k_fused(
    const float* __restrict__ emb, const int* __restrict__ labels,
    const int* __restrict__ graphs, const int* __restrict__ cats,
    char* __restrict__ ws, float* __restrict__ out) {
    __shared__ ushort sm[64 * 256];  // 32 KB
    cg::grid_group grid = cg::this_grid();

    ushort* Epb    = (ushort*)ws;
    int* zbase     = (int*)(ws + (size_t)N_NODES * DIM * 2);
    int* cnt       = zbase;
    int* tot       = cnt + NLAB * NGRAPH;
    int* P_count   = tot + NLAB;
    int* n_pos     = P_count + 1;
    float* acc_nce = (float*)(n_pos + 1);
    float* acc_pos = acc_nce + 1;
    float* s_glob  = acc_pos + 1;
    float* pos_glob= s_glob + N_NODES;
    int* idx_c     = (int*)(pos_glob + N_NODES);
    int* rc_c      = idx_c + N_NODES;
    int* meta      = rc_c + N_NODES;

    const int bid = blockIdx.x, tid = threadIdx.x;
    const int gtid = bid * NT + tid;
    const int nthreads = gridDim.x * NT;

    // ---- phase 0: zero counters/accumulators
    for (int i = gtid; i < ZN_INTS; i += nthreads) zbase[i] = 0;
    grid.sync();

    // ---- phase 1: histogram of conserved nodes per (label, graph)
    for (int i = gtid; i < N_NODES; i += nthreads) {
        if (cats[i] < 3) {
            atomicAdd(&cnt[labels[i] * NGRAPH + graphs[i]], 1);
            atomicAdd(&tot[labels[i]], 1);
        }
    }
    grid.sync();

    // ---- phase 2: compact participating nodes
    for (int i = gtid; i < N_NODES; i += nthreads) {
        if (cats[i] < 3) {
            int lb = labels[i], g = graphs[i];
            int rc = tot[lb] - cnt[lb * NGRAPH + g];
            if (rc > 0) {
                int p = atomicAdd(P_count, 1);
                idx_c[p] = i;
                meta[p] = (lb << 4) | g;
                rc_c[p] = rc;
                atomicAdd(n_pos, rc);
            }
        }
    }
    __threadfence();
    grid.sync();

    const int P = *P_count;
    const int ntiles = (P + 63) >> 6;

    // ---- phase 3: gather + L2-normalize + bf16 cast; zero tail rows of padded tiles
    {
        int nwaves = nthreads >> 6;
        int wv = gtid >> 6, lane = gtid & 63;
        int prows = ntiles * 64;
        for (int p = wv; p < prows; p += nwaves) {
            ushort4 o = make_ushort4(0, 0, 0, 0);
            if (p < P) {
                int row = idx_c[p];
                float4 v = *(const float4*)&emb[(size_t)row * DIM + lane * 4];
                float ss = v.x * v.x + v.y * v.y + v.z * v.z + v.w * v.w;
                #pragma unroll
                for (int off = 32; off; off >>= 1) ss += __shfl_xor(ss, off, 64);
                float inv = 1.0f / fmaxf(sqrtf(ss), 1e-12f);
                o.x = f2bf(v.x * inv); o.y = f2bf(v.y * inv);
                o.z = f2bf(v.z * inv); o.w = f2bf(v.w * inv);
            }
            *(ushort4*)&Epb[(size_t)p * DIM + lane * 4] = o;
        }
    }
    __threadfence();
    grid.sync();

    // ---- phase 4: persistent-block MFMA main loop over (rt, slice) items
    {
        const int w = tid >> 6, l = tid & 63;
        const int nitems = ntiles * NSLICE;
        for (int item = bid; item < nitems; item += gridDim.x) {
            int rt = item >> 4;
            int slice = item & (NSLICE - 1);
            int rowbase = rt * 64;

            #pragma unroll
            for (int it = 0; it < 8; ++it) {
                int u = it * 256 + tid;
                int G = u >> 6, l6 = u & 63;
                int rl = l6 & 15, sub = l6 >> 4;
                int r = rowbase + (G >> 3) * 16 + rl;
                int k0 = (G & 7) * 32 + sub * 8;
                uint4 v = *(const uint4*)&Epb[(size_t)r * DIM + k0];
                *(uint4*)&sm[u * 8] = v;
            }
            __syncthreads();
            short8 af[2][8];
            #pragma unroll
            for (int rg = 0; rg < 2; ++rg) {
                int rgi = (w & 1) * 2 + rg;
                #pragma unroll
                for (int ks = 0; ks < 8; ++ks)
                    af[rg][ks] = *(const short8*)&sm[((rgi * 8 + ks) * 64 + l) * 8];
            }
            int mp[8];
            #pragma unroll
            for (int rg = 0; rg < 2; ++rg)
                #pragma unroll
                for (int j = 0; j < 4; ++j)
                    mp[rg * 4 + j] = meta[rowbase + (w & 1) * 32 + rg * 16 + (l >> 4) * 4 + j];

            float s_acc[8] = {0.f, 0.f, 0.f, 0.f, 0.f, 0.f, 0.f, 0.f};
            float p_acc[8] = {0.f, 0.f, 0.f, 0.f, 0.f, 0.f, 0.f, 0.f};
            int cgi0 = (w >> 1) * 2, cgi1 = cgi0 + 1;
            __syncthreads();

            for (int ct = slice; ct < ntiles; ct += NSLICE) {
                int colbase = ct * 64;
                #pragma unroll
                for (int it = 0; it < 8; ++it) {
                    int u = it * 256 + tid;
                    int G = u >> 6, l6 = u & 63;
                    int rl = l6 & 15, sub = l6 >> 4;
                    int r = colbase + (G >> 3) * 16 + rl;
                    int k0 = (G & 7) * 32 + sub * 8;
                    uint4 v = *(const uint4*)&Epb[(size_t)r * DIM + k0];
                    *(uint4*)&sm[u * 8] = v;
                }
                __syncthreads();
                f32x4 acc00 = {0.f, 0.f, 0.f, 0.f}, acc01 = {0.f, 0.f, 0.f, 0.f};
                f32x4 acc10 = {0.f, 0.f, 0.f, 0.f}, acc11 = {0.f, 0.f, 0.f, 0.f};
                #pragma unroll
                for (int ks = 0; ks < 8; ++ks) {
                    short8 b0 = *(const short8*)&sm[((cgi0 * 8 + ks) * 64 + l) * 8];
                    short8 b1 = *(const short8*)&sm[((cgi1 * 8 + ks) * 64 + l) * 8];
                    acc00 = __builtin_amdgcn_mfma_f32_16x16x32_bf16(af[0][ks], b0, acc00, 0, 0, 0);
                    acc01 = __builtin_amdgcn_mfma_f32_16x16x32_bf16(af[0][ks], b1, acc01, 0, 0, 0);
                    acc10 = __builtin_amdgcn_mfma_f32_16x16x32_bf16(af[1][ks], b0, acc10, 0, 0, 0);
                    acc11 = __builtin_amdgcn_mfma_f32_16x16x32_bf16(af[1][ks], b1, acc11, 0, 0, 0);
                }
                #pragma unroll
                for (int cg2 = 0; cg2 < 2; ++cg2) {
                    int q = colbase + (cgi0 + cg2) * 16 + (l & 15);
                    bool vq = q < P;
                    int mq = meta[q];
                    #pragma unroll
                    for (int rg = 0; rg < 2; ++rg) {
                        f32x4 a = (rg == 0) ? (cg2 == 0 ? acc00 : acc01)
                                            : (cg2 == 0 ? acc10 : acc11);
                        #pragma unroll
                        for (int j = 0; j < 4; ++j) {
                            float sv = a[j];
                            int mpv = mp[rg * 4 + j];
                            bool val = vq && (((mq ^ mpv) & 15) != 0);
                            float e = __expf(sv * INV_T);
                            s_acc[rg * 4 + j] += val ? e : 0.f;
                            p_acc[rg * 4 + j] += (val && ((mq >> 4) == (mpv >> 4))) ? sv : 0.f;
                        }
                    }
                }
                __syncthreads();
            }
            #pragma unroll
            for (int off = 1; off < 16; off <<= 1)
                #pragma unroll
                for (int i = 0; i < 8; ++i) {
                    s_acc[i] += __shfl_xor(s_acc[i], off, 64);
                    p_acc[i] += __shfl_xor(p_acc[i], off, 64);
                }
            if ((l & 15) == 0) {
                #pragma unroll
                for (int rg = 0; rg < 2; ++rg)
                    #pragma unroll
                    for (int j = 0; j < 4; ++j) {
                        int p = rowbase + (w & 1) * 32 + rg * 16 + (l >> 4) * 4 + j;
                        if (p < P) {
                            atomicAdd(&s_glob[p], s_acc[rg * 4 + j]);
                            atomicAdd(&pos_glob[p], p_acc[rg * 4 + j]);
                        }
                    }
            }
        }
    }
    __threadfence();
    grid.sync();

    // ---- phase 5: per-row lse * rc, block reduce, global accumulate
    {
        float nce_l = 0.f, pos_l = 0.f;
        for (int p = gtid; p < P; p += nthreads) {
            nce_l += (float)rc_c[p] * logf(s_glob[p]);
            pos_l += pos_glob[p];
        }
        float* red = (float*)sm;
        red[tid] = nce_l;
        red[NT + tid] = pos_l;
        __syncthreads();
        for (int wd = 128; wd; wd >>= 1) {
            if (tid < wd) {
                red[tid] += red[tid + wd];
                red[NT + tid] += red[NT + tid + wd];
            }
            __syncthreads();
        }
        if (tid == 0) {
            atomicAdd(acc_nce, red[0]);
            atomicAdd(acc_pos, red[NT]);
        }
    }
    __threadfence();
    grid.sync();

    // ---- phase 6: finalize
    if (gtid == 0) {
        int npos = *n_pos;
        float result = 0.f;
        if (npos > 0) {
            float possum = *acc_pos;
            float n_pairs = (float)(npos / 2);
            float pos_loss = (n_pairs - 0.5f * possum) / n_pairs;
            float nce = (*acc_nce - possum * INV_T) / (float)npos;
            result = pos_loss + nce;
        }
        out[0] = result;
    }
}

// ===================== fallback multi-kernel path (round-2 proven) =====================
__global__ void k_counts(const int* __restrict__ labels, const int* __restrict__ graphs,
                         const int* __restrict__ cats, int* __restrict__ cnt, int* __restrict__ tot) {
    int i = blockIdx.x * 256 + threadIdx.x;
    if (i >= N_NODES) return;
    if (cats[i] < 3) {
        atomicAdd(&cnt[labels[i] * NGRAPH + graphs[i]], 1);
        atomicAdd(&tot[labels[i]], 1);
    }
}

__global__ void k_compact(const int* __restrict__ labels, const int* __restrict__ graphs,
                          const int* __restrict__ cats, const int* __restrict__ cnt,
                          const int* __restrict__ tot, int* P_count, int* n_pos,
                          int* __restrict__ idx_c, int* __restrict__ meta,
                          int* __restrict__ rc_c) {
    int i = blockIdx.x * 256 + threadIdx.x;
    if (i >= N_NODES) return;
    if (cats[i] < 3) {
        int l = labels[i], g = graphs[i];
        int rc = tot[l] - cnt[l * NGRAPH + g];
        if (rc > 0) {
            int p = atomicAdd(P_count, 1);
            idx_c[p] = i;
            meta[p] = (l << 4) | g;
            rc_c[p] = rc;
            atomicAdd(n_pos, rc);
        }
    }
}

__global__ __launch_bounds__(256) void k_gather(const float* __restrict__ emb,
                                                const int* __restrict__ P_count,
                                                const int* __restrict__ idx_c,
                                                ushort* __restrict__ Epb) {
    int w = threadIdx.x >> 6, lane = threadIdx.x & 63;
    int p = blockIdx.x * 4 + w;
    int P = *P_count;
    ushort4 o = make_ushort4(0, 0, 0, 0);
    if (p < P) {
        int row = idx_c[p];
        float4 v = *(const float4*)&emb[(size_t)row * DIM + lane * 4];
        float ss = v.x * v.x + v.y * v.y + v.z * v.z + v.w * v.w;
        #pragma unroll
        for (int off = 32; off; off >>= 1) ss += __shfl_xor(ss, off, 64);
        float inv = 1.0f / fmaxf(sqrtf(ss), 1e-12f);
        o.x = f2bf(v.x * inv); o.y = f2bf(v.y * inv);
        o.z = f2bf(v.z * inv); o.w = f2bf(v.w * inv);
    }
    *(ushort4*)&Epb[(size_t)p * DIM + lane * 4] = o;
}

__global__ __launch_bounds__(256) void k_main(
    const ushort* __restrict__ Epb, const int* __restrict__ P_count,
    const int* __restrict__ meta, float* __restrict__ s_glob, float* __restrict__ pos_glob) {
    __shared__ ushort sm[64 * 256];
    int P = *P_count;
    int rt = blockIdx.x;
    int ntiles = (P + 63) >> 6;
    if (rt >= ntiles) return;
    int slice = blockIdx.y;
    int t = threadIdx.x;
    int w = t >> 6, l = t & 63;
    int rowbase = rt * 64;

    #pragma unroll
    for (int it = 0; it < 8; ++it) {
        int u = it * 256 + t;
        int G = u >> 6, l6 = u & 63;
        int rl = l6 & 15, sub = l6 >> 4;
        int r = rowbase + (G >> 3) * 16 + rl;
        int k0 = (G & 7) * 32 + sub * 8;
        uint4 v = *(const uint4*)&Epb[(size_t)r * DIM + k0];
        *(uint4*)&sm[u * 8] = v;
    }
    __syncthreads();
    short8 af[2][8];
    #pragma unroll
    for (int rg = 0; rg < 2; ++rg) {
        int rgi = (w & 1) * 2 + rg;
        #pragma unroll
        for (int ks = 0; ks < 8; ++ks)
            af[rg][ks] = *(const short8*)&sm[((rgi * 8 + ks) * 64 + l) * 8];
    }
    int mp[8];
    #pragma unroll
    for (int rg = 0; rg < 2; ++rg)
        #pragma unroll
        for (int j = 0; j < 4; ++j)
            mp[rg * 4 + j] = meta[rowbase + (w & 1) * 32 + rg * 16 + (l >> 4) * 4 + j];

    float s_acc[8] = {0.f, 0.f, 0.f, 0.f, 0.f, 0.f, 0.f, 0.f};
    float p_acc[8] = {0.f, 0.f, 0.f, 0.f, 0.f, 0.f, 0.f, 0.f};
    int cgi0 = (w >> 1) * 2, cgi1 = cgi0 + 1;
    __syncthreads();

    for (int ct = slice; ct < ntiles; ct += NSLICE) {
        int colbase = ct * 64;
        #pragma unroll
        for (int it = 0; it < 8; ++it) {
            int u = it * 256 + t;
            int G = u >> 6, l6 = u & 63;
            int rl = l6 & 15, sub = l6 >> 4;
            int r = colbase + (G >> 3) * 16 + rl;
            int k0 = (G & 7) * 32 + sub * 8;
            uint4 v = *(const uint4*)&Epb[(size_t)r * DIM + k0];
            *(uint4*)&sm[u * 8] = v;
        }
        __syncthreads();
        f32x4 acc00 = {0.f, 0.f, 0.f, 0.f}, acc01 = {0.f, 0.f, 0.f, 0.f};
        f32x4 acc10 = {0.f, 0.f, 0.f, 0.f}, acc11 = {0.f, 0.f, 0.f, 0.f};
        #pragma unroll
        for (int ks = 0; ks < 8; ++ks) {
            short8 b0 = *(const short8*)&sm[((cgi0 * 8 + ks) * 64 + l) * 8];
            short8 b1 = *(const short8*)&sm[((cgi1 * 8 + ks) * 64 + l) * 8];
            acc00 = __builtin_amdgcn_mfma_f32_16x16x32_bf16(af[0][ks], b0, acc00, 0, 0, 0);
            acc01 = __builtin_amdgcn_mfma_f32_16x16x32_bf16(af[0][ks], b1, acc01, 0, 0, 0);
            acc10 = __builtin_amdgcn_mfma_f32_16x16x32_bf16(af[1][ks], b0, acc10, 0, 0, 0);
            acc11 = __builtin_amdgcn_mfma_f32_16x16x32_bf16(af[1][ks], b1, acc11, 0, 0, 0);
        }
        #pragma unroll
        for (int cg2 = 0; cg2 < 2; ++cg2) {
            int q = colbase + (cgi0 + cg2) * 16 + (l & 15);
            bool vq = q < P;
            int mq = meta[q];
            #pragma unroll
            for (int rg = 0; rg < 2; ++rg) {
                f32x4 a = (rg == 0) ? (cg2 == 0 ? acc00 : acc01)
                                    : (cg2 == 0 ? acc10 : acc11);
                #pragma unroll
                for (int j = 0; j < 4; ++j) {
                    float sv = a[j];
                    int mpv = mp[rg * 4 + j];
                    bool val = vq && (((mq ^ mpv) & 15) != 0);
                    float e = __expf(sv * INV_T);
                    s_acc[rg * 4 + j] += val ? e : 0.f;
                    p_acc[rg * 4 + j] += (val && ((mq >> 4) == (mpv >> 4))) ? sv : 0.f;
                }
            }
        }
        __syncthreads();
    }
    #pragma unroll
    for (int off = 1; off < 16; off <<= 1)
        #pragma unroll
        for (int i = 0; i < 8; ++i) {
            s_acc[i] += __shfl_xor(s_acc[i], off, 64);
            p_acc[i] += __shfl_xor(p_acc[i], off, 64);
        }
    if ((l & 15) == 0) {
        #pragma unroll
        for (int rg = 0; rg < 2; ++rg)
            #pragma unroll
            for (int j = 0; j < 4; ++j) {
                int p = rowbase + (w & 1) * 32 + rg * 16 + (l >> 4) * 4 + j;
                if (p < P) {
                    atomicAdd(&s_glob[p], s_acc[rg * 4 + j]);
                    atomicAdd(&pos_glob[p], p_acc[rg * 4 + j]);
                }
            }
    }
}

__global__ __launch_bounds__(256) void k_reduce(
    const int* __restrict__ P_count, const int* __restrict__ n_pos_p,
    const int* __restrict__ rc_c, const float* __restrict__ s_glob,
    const float* __restrict__ pos_glob, float* __restrict__ out) {
    __shared__ float red[512];
    int P = *P_count;
    float nce_local = 0.f, pos_local = 0.f;
    for (int p = threadIdx.x; p < P; p += 256) {
        nce_local += (float)rc_c[p] * logf(s_glob[p]);
        pos_local += pos_glob[p];
    }
    red[threadIdx.x] = nce_local;
    red[256 + threadIdx.x] = pos_local;
    __syncthreads();
    for (int wd = 128; wd; wd >>= 1) {
        if (threadIdx.x < (unsigned)wd) {
            red[threadIdx.x] += red[threadIdx.x + wd];
            red[256 + threadIdx.x] += red[256 + threadIdx.x + wd];
        }
        __syncthreads();
    }
    if (threadIdx.x == 0) {
        int npos = *n_pos_p;
        float result = 0.f;
        if (npos > 0) {
            float possum = red[256];
            float n_pairs = (float)(npos / 2);
            float pos_loss = (n_pairs - 0.5f * possum) / n_pairs;
            float nce = (red[0] - possum * INV_T) / (float)npos;
            result = pos_loss + nce;
        }
        out[0] = result;
    }
}

extern "C" void kernel_launch(void* const* d_in, const int* in_sizes, int n_in,
                              void* d_out, int out_size, void* d_ws, size_t ws_size,
                              hipStream_t stream) {
    const float* emb  = (const float*)d_in[0];
    const int* labels = (const int*)d_in[1];
    const int* graphs = (const int*)d_in[2];
    const int* cats   = (const int*)d_in[3];
    char* ws   = (char*)d_ws;
    float* outp = (float*)d_out;

    // workspace pointers (host mirror of device layout)
    ushort* Epb    = (ushort*)ws;
    int* zbase     = (int*)(ws + (size_t)N_NODES * DIM * 2);
    int* cnt       = zbase;
    int* tot       = cnt + NLAB * NGRAPH;
    int* P_count   = tot + NLAB;
    int* n_pos     = P_count + 1;
    float* acc_nce = (float*)(n_pos + 1);
    float* acc_pos = acc_nce + 1;
    float* s_glob  = acc_pos + 1;
    float* pos_glob= s_glob + N_NODES;
    int* idx_c     = (int*)(pos_glob + N_NODES);
    int* rc_c      = idx_c + N_NODES;
    int* meta      = rc_c + N_NODES;
    (void)acc_nce; (void)acc_pos;

    // size the cooperative grid from the runtime's occupancy answer
    int devId = 0;
    (void)hipGetDevice(&devId);
    int blocksPerCU = 0, numCU = 0;
    hipError_t occErr = hipOccupancyMaxActiveBlocksPerMultiprocessor(
        &blocksPerCU, (const void*)k_fused, NT, 0);
    hipError_t attrErr = hipDeviceGetAttribute(
        &numCU, hipDeviceAttributeMultiprocessorCount, devId);

    int nb = 0;
    if (occErr == hipSuccess && attrErr == hipSuccess && blocksPerCU > 0 && numCU > 0) {
        nb = blocksPerCU * numCU;
        if (nb > NB_MAX) nb = NB_MAX;
    }

    hipError_t launchErr = hipErrorUnknown;
    if (nb > 0) {
        void* args[6] = {(void*)&emb, (void*)&labels, (void*)&graphs,
                         (void*)&cats, (void*)&ws, (void*)&outp};
        launchErr = hipLaunchCooperativeKernel((const void*)k_fused, dim3(nb), dim3(NT),
                                               args, 0, stream);
    }
    if (launchErr != hipSuccess) {
        // fallback: proven multi-kernel path on the same workspace layout
        hipMemsetAsync(zbase, 0, (size_t)ZN_INTS * 4, stream);
        k_counts<<<N_NODES / 256, 256, 0, stream>>>(labels, graphs, cats, cnt, tot);
        k_compact<<<N_NODES / 256, 256, 0, stream>>>(labels, graphs, cats, cnt, tot,
                                                     P_count, n_pos, idx_c, meta, rc_c);
        k_gather<<<N_NODES / 4, 256, 0, stream>>>(emb, P_count, idx_c, Epb);
        dim3 grid(N_NODES / 64, NSLICE);
        k_main<<<grid, 256, 0, stream>>>(Epb, P_count, meta, s_glob, pos_glob);
        k_reduce<<<1, 256, 0, stream>>>(P_count, n_pos, rc_c, s_glob, pos_glob, outp);
    }
}

// Round 15
// 268.053 us; speedup vs baseline: 1.4684x; 1.4684x over previous
//
#include <hip/hip_runtime.h>
#include <hip/hip_bf16.h>

#define N_NODES 8192
#define DIM 256
#define NLAB 2048
#define NGRAPH 16
#define NSLICE 16
#define INV_T 10.0f
// zeroed int region: cnt | tot | P_count | n_pos | done | s_glob | pos_glob
#define ZN_INTS (NLAB * NGRAPH + NLAB + 3 + 2 * N_NODES)

typedef __attribute__((ext_vector_type(8))) short short8;
typedef __attribute__((ext_vector_type(4))) float f32x4;

__device__ __forceinline__ ushort f2bf(float f) {
    uint u = __float_as_uint(f);
    return (ushort)((u + 0x7FFFu + ((u >> 16) & 1u)) >> 16);  // RNE
}

// ===================== k_prep: zero + histogram + compact (1 block, 1024 thr) =====================
__global__ __launch_bounds__(1024) void k_prep(
    const int* __restrict__ labels, const int* __restrict__ graphs,
    const int* __restrict__ cats, char* __restrict__ ws) {
    int* zbase   = (int*)(ws + (size_t)N_NODES * DIM * 2);
    int* cnt     = zbase;                    // 2048*16
    int* tot     = cnt + NLAB * NGRAPH;      // 2048
    int* P_count = tot + NLAB;               // 1
    int* n_pos   = P_count + 1;              // 1
    // done = n_pos+1 (zeroed, used by k_mainred)
    int* idx_c   = zbase + ZN_INTS;          // 8192 (after zeroed region)
    int* rc_c    = idx_c + N_NODES;
    int* meta    = rc_c + N_NODES;

    const int tid = threadIdx.x;

    // phase 0: zero counters + accumulators (51203 ints)
    for (int i = tid; i < ZN_INTS; i += 1024) zbase[i] = 0;
    __syncthreads();

    // phase 1: histogram of conserved nodes per (label, graph)
    for (int i = tid; i < N_NODES; i += 1024) {
        if (cats[i] < 3) {
            atomicAdd(&cnt[labels[i] * NGRAPH + graphs[i]], 1);
            atomicAdd(&tot[labels[i]], 1);
        }
    }
    __syncthreads();

    // phase 2: compact participating nodes (atomic reads: L2-coherent vs atomic writes above)
    for (int i = tid; i < N_NODES; i += 1024) {
        if (cats[i] < 3) {
            int lb = labels[i], g = graphs[i];
            int c  = atomicAdd(&cnt[lb * NGRAPH + g], 0);
            int tt = atomicAdd(&tot[lb], 0);
            int rc = tt - c;  // # positive partners
            if (rc > 0) {
                int p = atomicAdd(P_count, 1);
                idx_c[p] = i;
                meta[p] = (lb << 4) | g;
                rc_c[p] = rc;
                atomicAdd(n_pos, rc);
            }
        }
    }
}

// ===================== k_gather: gather + L2-normalize + bf16 cast =====================
__global__ __launch_bounds__(256) void k_gather(const float* __restrict__ emb,
                                                char* __restrict__ ws) {
    ushort* Epb  = (ushort*)ws;
    int* zbase   = (int*)(ws + (size_t)N_NODES * DIM * 2);
    int* P_count = zbase + NLAB * NGRAPH + NLAB;
    int* idx_c   = zbase + ZN_INTS;

    int w = threadIdx.x >> 6, lane = threadIdx.x & 63;
    int p = blockIdx.x * 4 + w;
    int P = *P_count;
    ushort4 o = make_ushort4(0, 0, 0, 0);
    if (p < P) {
        int row = idx_c[p];
        float4 v = *(const float4*)&emb[(size_t)row * DIM + lane * 4];
        float ss = v.x * v.x + v.y * v.y + v.z * v.z + v.w * v.w;
        #pragma unroll
        for (int off = 32; off; off >>= 1) ss += __shfl_xor(ss, off, 64);
        float inv = 1.0f / fmaxf(sqrtf(ss), 1e-12f);
        o.x = f2bf(v.x * inv); o.y = f2bf(v.y * inv);
        o.z = f2bf(v.z * inv); o.w = f2bf(v.w * inv);
    }
    *(ushort4*)&Epb[(size_t)p * DIM + lane * 4] = o;  // rows >= P zero-filled
}

// ===================== k_mainred: MFMA tiles + exp/pos accumulation + last-block reduce =====================
__global__ __launch_bounds__(256) void k_mainred(char* __restrict__ ws, float* __restrict__ out) {
    __shared__ ushort sm[64 * 256];  // 32 KB: A tile, then B tiles, then reduce scratch
    __shared__ int is_last;

    ushort* Epb    = (ushort*)ws;
    int* zbase     = (int*)(ws + (size_t)N_NODES * DIM * 2);
    int* cnt       = zbase;
    int* tot       = cnt + NLAB * NGRAPH;
    int* P_count   = tot + NLAB;
    int* n_pos     = P_count + 1;
    int* done      = n_pos + 1;
    float* s_glob  = (float*)(done + 1);     // 8192
    float* pos_glob= s_glob + N_NODES;       // 8192
    int* idx_c     = zbase + ZN_INTS;
    int* rc_c      = idx_c + N_NODES;
    int* meta      = rc_c + N_NODES;
    (void)idx_c;

    const int P = *P_count;
    const int ntiles = (P + 63) >> 6;
    const int rt = blockIdx.x;
    const int slice = blockIdx.y;
    const int t = threadIdx.x;
    const int w = t >> 6, l = t & 63;

    if (rt < ntiles) {
        int rowbase = rt * 64;
        // stage A tile in fragment order: unit u=(G*64+sub*16+rl), G=rg8*8+ks
        #pragma unroll
        for (int it = 0; it < 8; ++it) {
            int u = it * 256 + t;
            int G = u >> 6, l6 = u & 63;
            int rl = l6 & 15, sub = l6 >> 4;
            int r = rowbase + (G >> 3) * 16 + rl;
            int k0 = (G & 7) * 32 + sub * 8;
            uint4 v = *(const uint4*)&Epb[(size_t)r * DIM + k0];
            *(uint4*)&sm[u * 8] = v;
        }
        __syncthreads();
        short8 af[2][8];
        #pragma unroll
        for (int rg = 0; rg < 2; ++rg) {
            int rgi = (w & 1) * 2 + rg;
            #pragma unroll
            for (int ks = 0; ks < 8; ++ks)
                af[rg][ks] = *(const short8*)&sm[((rgi * 8 + ks) * 64 + l) * 8];
        }
        int mp[8];
        #pragma unroll
        for (int rg = 0; rg < 2; ++rg)
            #pragma unroll
            for (int j = 0; j < 4; ++j)
                mp[rg * 4 + j] = meta[rowbase + (w & 1) * 32 + rg * 16 + (l >> 4) * 4 + j];

        float s_acc[8] = {0.f, 0.f, 0.f, 0.f, 0.f, 0.f, 0.f, 0.f};
        float p_acc[8] = {0.f, 0.f, 0.f, 0.f, 0.f, 0.f, 0.f, 0.f};
        int cgi0 = (w >> 1) * 2, cgi1 = cgi0 + 1;
        __syncthreads();  // A fragments hoisted; sm free for B

        for (int ct = slice; ct < ntiles; ct += NSLICE) {
            int colbase = ct * 64;
            #pragma unroll
            for (int it = 0; it < 8; ++it) {
                int u = it * 256 + t;
                int G = u >> 6, l6 = u & 63;
                int rl = l6 & 15, sub = l6 >> 4;
                int r = colbase + (G >> 3) * 16 + rl;
                int k0 = (G & 7) * 32 + sub * 8;
                uint4 v = *(const uint4*)&Epb[(size_t)r * DIM + k0];
                *(uint4*)&sm[u * 8] = v;
            }
            __syncthreads();
            f32x4 acc00 = {0.f, 0.f, 0.f, 0.f}, acc01 = {0.f, 0.f, 0.f, 0.f};
            f32x4 acc10 = {0.f, 0.f, 0.f, 0.f}, acc11 = {0.f, 0.f, 0.f, 0.f};
            #pragma unroll
            for (int ks = 0; ks < 8; ++ks) {
                short8 b0 = *(const short8*)&sm[((cgi0 * 8 + ks) * 64 + l) * 8];
                short8 b1 = *(const short8*)&sm[((cgi1 * 8 + ks) * 64 + l) * 8];
                acc00 = __builtin_amdgcn_mfma_f32_16x16x32_bf16(af[0][ks], b0, acc00, 0, 0, 0);
                acc01 = __builtin_amdgcn_mfma_f32_16x16x32_bf16(af[0][ks], b1, acc01, 0, 0, 0);
                acc10 = __builtin_amdgcn_mfma_f32_16x16x32_bf16(af[1][ks], b0, acc10, 0, 0, 0);
                acc11 = __builtin_amdgcn_mfma_f32_16x16x32_bf16(af[1][ks], b1, acc11, 0, 0, 0);
            }
            // epilogue: C/D layout col=lane&15, row=(lane>>4)*4+reg
            #pragma unroll
            for (int cg2 = 0; cg2 < 2; ++cg2) {
                int q = colbase + (cgi0 + cg2) * 16 + (l & 15);
                bool vq = q < P;
                int mq = meta[q];
                #pragma unroll
                for (int rg = 0; rg < 2; ++rg) {
                    f32x4 a = (rg == 0) ? (cg2 == 0 ? acc00 : acc01)
                                        : (cg2 == 0 ? acc10 : acc11);
                    #pragma unroll
                    for (int j = 0; j < 4; ++j) {
                        float sv = a[j];
                        int mpv = mp[rg * 4 + j];
                        bool val = vq && (((mq ^ mpv) & 15) != 0);  // valid <=> diff graph
                        float e = __expf(sv * INV_T);               // fixed max 0 (|logit|<=10)
                        s_acc[rg * 4 + j] += val ? e : 0.f;
                        p_acc[rg * 4 + j] += (val && ((mq >> 4) == (mpv >> 4))) ? sv : 0.f;
                    }
                }
            }
            __syncthreads();
        }
        // 16-lane (column) reduce, then atomics into per-row accumulators
        #pragma unroll
        for (int off = 1; off < 16; off <<= 1)
            #pragma unroll
            for (int i = 0; i < 8; ++i) {
                s_acc[i] += __shfl_xor(s_acc[i], off, 64);
                p_acc[i] += __shfl_xor(p_acc[i], off, 64);
            }
        if ((l & 15) == 0) {
            #pragma unroll
            for (int rg = 0; rg < 2; ++rg)
                #pragma unroll
                for (int j = 0; j < 4; ++j) {
                    int p = rowbase + (w & 1) * 32 + rg * 16 + (l >> 4) * 4 + j;
                    if (p < P) {
                        atomicAdd(&s_glob[p], s_acc[rg * 4 + j]);
                        atomicAdd(&pos_glob[p], p_acc[rg * 4 + j]);
                    }
                }
        }
    }

    // ---- all blocks (incl. early-outs): done-count; last block reduces & finalizes
    __threadfence();
    __syncthreads();
    if (t == 0) {
        int total = gridDim.x * gridDim.y;
        int old = atomicAdd(done, 1);
        is_last = (old == total - 1) ? 1 : 0;
    }
    __syncthreads();
    if (is_last) {
        float nce_l = 0.f, pos_l = 0.f;
        for (int p = t; p < P; p += 256) {
            float sv = atomicAdd(&s_glob[p], 0.f);    // L2-coherent read of atomic sums
            float pv = atomicAdd(&pos_glob[p], 0.f);
            nce_l += (float)rc_c[p] * logf(sv);       // fixed max 0
            pos_l += pv;
        }
        float* red = (float*)sm;
        red[t] = nce_l;
        red[256 + t] = pos_l;
        __syncthreads();
        for (int wd = 128; wd; wd >>= 1) {
            if (t < wd) {
                red[t] += red[t + wd];
                red[256 + t] += red[256 + t + wd];
            }
            __syncthreads();
        }
        if (t == 0) {
            int npos = *n_pos;
            float result = 0.f;
            if (npos > 0) {
                float possum = red[256];
                float n_pairs = (float)(npos / 2);
                float pos_loss = (n_pairs - 0.5f * possum) / n_pairs;
                float nce = (red[0] - possum * INV_T) / (float)npos;
                result = pos_loss + nce;
            }
            out[0] = result;
        }
    }
}

extern "C" void kernel_launch(void* const* d_in, const int* in_sizes, int n_in,
                              void* d_out, int out_size, void* d_ws, size_t ws_size,
                              hipStream_t stream) {
    const float* emb  = (const float*)d_in[0];
    const int* labels = (const int*)d_in[1];
    const int* graphs = (const int*)d_in[2];
    const int* cats   = (const int*)d_in[3];
    char* ws    = (char*)d_ws;
    float* outp = (float*)d_out;

    k_prep<<<1, 1024, 0, stream>>>(labels, graphs, cats, ws);
    k_gather<<<N_NODES / 4, 256, 0, stream>>>(emb, ws);
    dim3 grid(N_NODES / 64, NSLICE);
    k_mainred<<<grid, 256, 0, stream>>>(ws, outp);
}